// Round 11
// baseline (115.009 us; speedup 1.0000x reference)
//
#include <hip/hip_runtime.h>

namespace {
constexpr int Bn = 32, Dn = 64, Hn = 64, Wn = 64;
constexpr int PLANE = Hn * Wn;   // 4096
constexpr int NW  = 8;           // waves per block, splitting d
constexpr int DPW = Dn / NW;     // 8 d-slices per wave
constexpr int RSTR = 68;         // stage tile row stride (floats): 272B, 16B-aligned rows
constexpr int REG  = 1152;       // floats per wave LDS region (union: red 9*64*f2 = stage)
constexpr float SCALE = 0.125f;  // 64^-0.5
typedef float f4a __attribute__((ext_vector_type(4), aligned(16)));
}

__global__ __launch_bounds__(512, 8) void dilate_attn_kernel(
    const float* __restrict__ q, const float* __restrict__ k,
    const float* __restrict__ v, float* __restrict__ out)
{
    // Per-wave union region: [9][64] float2 reduction slice OR k/v stage tile.
    // Sequencing makes the overlay safe: stage reads complete (in-order DS +
    // explicit lgkmcnt) before the red overwrite; barrier2 completes before
    // v-staging overwrites red.
    __shared__ float lds[NW][REG];   // 36864 B; 4 blocks/CU = 147 KB

    const int t  = threadIdx.x;
    const int l  = t & 63;
    const int wv = t >> 6;              // wave id -> d-eighth
    const int ci = l & 31;              // lane col-pair index
    const int lr = l >> 5;              // row within stripe (0..1)
    const int c  = ci * 2;              // first of this lane's 2 pixel cols

    // XCD-chunked swizzle: 1024 blocks -> 128 contiguous (b,stripe) per XCD
    const int bid = blockIdx.x;
    const int swz = (bid & 7) * 128 + (bid >> 3);
    const int b      = swz >> 5;
    const int stripe = swz & 31;
    const int hr     = stripe * 2 + lr; // this lane's pixel row

    const int  base = b * Dn * PLANE;
    const bool ci0 = (ci == 0), ci31 = (ci == 31);

    // ---- stage tile geometry (4 rows x 64 cols, rows = clamp(2*stripe-1+i)) --
    float* const sbase = &lds[wv][4];             // +4 guard for col -1 reads
    const int wrow = l >> 4;                      // writer: 4 lanes-groups x 4 rows
    const int wcol = (l & 15) * 4;
    float* const swr = sbase + wrow * RSTR + wcol;          // 16B-aligned
    const int grow = min(max(stripe * 2 - 1 + wrow, 0), Hn - 1);
    const int soff = grow * Wn + wcol;            // global stage offset, in-bounds
    // reader row bases: loop-invariant, window cols c-1..c+2 (pad/guard absorb OOB)
    const float* rb0 = sbase + (lr + 0) * RSTR + (c - 1);
    const float* rb1 = sbase + (lr + 1) * RSTR + (c - 1);
    const float* rb2 = sbase + (lr + 2) * RSTR + (c - 1);

    bool rok[3];
#pragma unroll
    for (int di = 0; di < 3; ++di) {
        const int kr = hr - 1 + di;
        rok[di] = (kr >= 0) && (kr < Hn);
    }
    const int qoff = hr * Wn + c;

    float a0[9], a1[9];
#pragma unroll
    for (int n = 0; n < 9; ++n) { a0[n] = 0.0f; a1[n] = 0.0f; }

    // accumulate one d-slice from the staged tile: uniform map, no selects
    auto ACC = [&](const float2 qv) {
#pragma unroll
        for (int di = 0; di < 3; ++di) {
            const float* rb = (di == 0) ? rb0 : (di == 1) ? rb1 : rb2;
            const float w0 = rb[0], w1 = rb[1], w2 = rb[2], w3 = rb[3];
            a0[di * 3 + 0] = fmaf(qv.x, w0, a0[di * 3 + 0]);
            a0[di * 3 + 1] = fmaf(qv.x, w1, a0[di * 3 + 1]);
            a0[di * 3 + 2] = fmaf(qv.x, w2, a0[di * 3 + 2]);
            a1[di * 3 + 0] = fmaf(qv.y, w1, a1[di * 3 + 0]);
            a1[di * 3 + 1] = fmaf(qv.y, w2, a1[di * 3 + 1]);
            a1[di * 3 + 2] = fmaf(qv.y, w3, a1[di * 3 + 2]);
        }
    };

    // -------- Phase 1: stage k slice -> LDS, dot with q, depth-2 prefetch ----
    {
        const float* kp = k + base + wv * DPW * PLANE + soff;
        const float* qp = q + base + wv * DPW * PLANE + qoff;
        f4a kgA = *(const f4a*)kp; kp += PLANE;
        f4a kgB = *(const f4a*)kp; kp += PLANE;
#pragma unroll 2
        for (int ds = 0; ds < DPW; ++ds) {
            const float2 qv = *(const float2*)qp; qp += PLANE;
            *(f4a*)swr = kgA;                      // ds_write_b128 (vmcnt on kgA)
            if (ds + 2 < DPW) { kgA = *(const f4a*)kp; kp += PLANE; }
            asm volatile("s_waitcnt lgkmcnt(0)" ::: "memory");
            ACC(qv);                               // ds_reads + 18 FMA
            // rotate
            { f4a tmp = kgB; kgB = kgA; kgA = tmp; }
        }
    }

    // -------- prefetch v ds=0 global load before the reduction wall ---------
    const float* vp = v + base + wv * DPW * PLANE + soff;
    f4a vg0 = *(const f4a*)vp; vp += PLANE;

    // -------- cross-wave reduction (full-read, 2 barriers) ------------------
    {
        float2* redw = (float2*)&lds[wv][0];       // own region as [9][64] f2
#pragma unroll
        for (int n = 0; n < 9; ++n) redw[n * 64 + l] = make_float2(a0[n], a1[n]);
    }
    __syncthreads();
#pragma unroll
    for (int n = 0; n < 9; ++n) {
        float2 s = ((const float2*)&lds[0][0])[n * 64 + l];
#pragma unroll
        for (int sw = 1; sw < NW; ++sw) {
            const float2 p = ((const float2*)&lds[sw][0])[n * 64 + l];
            s.x += p.x; s.y += p.y;
        }
        a0[n] = s.x; a1[n] = s.y;
    }
    __syncthreads();   // everyone consumed red; regions reusable for v staging

    // -------- zero invalid-position SCORES (reference: q . 0-pad = 0) -------
#pragma unroll
    for (int di = 0; di < 3; ++di)
#pragma unroll
        for (int dj = 0; dj < 3; ++dj) {
            const int n = di * 3 + dj;
            a0[n] = (rok[di] && (dj != 0 || !ci0))  ? a0[n] : 0.0f;
            a1[n] = (rok[di] && (dj != 2 || !ci31)) ? a1[n] : 0.0f;
        }
#pragma unroll
    for (int n = 0; n < 9; ++n) { a0[n] *= SCALE; a1[n] *= SCALE; }
    float m0 = a0[0], m1 = a1[0];
#pragma unroll
    for (int n = 1; n < 9; ++n) { m0 = fmaxf(m0, a0[n]); m1 = fmaxf(m1, a1[n]); }
    float s0 = 0.0f, s1 = 0.0f;
#pragma unroll
    for (int n = 0; n < 9; ++n) {
        a0[n] = __expf(a0[n] - m0); s0 += a0[n];
        a1[n] = __expf(a1[n] - m1); s1 += a1[n];
    }
    const float i0 = 1.0f / s0, i1 = 1.0f / s1;
#pragma unroll
    for (int n = 0; n < 9; ++n) { a0[n] *= i0; a1[n] *= i1; }

    // -------- zero invalid-position WEIGHTS (reference: attn * v=0 there) ---
#pragma unroll
    for (int di = 0; di < 3; ++di)
#pragma unroll
        for (int dj = 0; dj < 3; ++dj) {
            const int n = di * 3 + dj;
            a0[n] = (rok[di] && (dj != 0 || !ci0))  ? a0[n] : 0.0f;
            a1[n] = (rok[di] && (dj != 2 || !ci31)) ? a1[n] : 0.0f;
        }

    auto PV = [&]() -> float2 {
        float o0 = 0.0f, o1 = 0.0f;
#pragma unroll
        for (int di = 0; di < 3; ++di) {
            const float* rb = (di == 0) ? rb0 : (di == 1) ? rb1 : rb2;
            const float w0 = rb[0], w1 = rb[1], w2 = rb[2], w3 = rb[3];
            o0 = fmaf(a0[di * 3 + 0], w0, o0);
            o0 = fmaf(a0[di * 3 + 1], w1, o0);
            o0 = fmaf(a0[di * 3 + 2], w2, o0);
            o1 = fmaf(a1[di * 3 + 0], w1, o1);
            o1 = fmaf(a1[di * 3 + 1], w2, o1);
            o1 = fmaf(a1[di * 3 + 2], w3, o1);
        }
        return make_float2(o0, o1);
    };

    // -------- Phase 2: stage v slice -> LDS, weighted sum, depth-2 prefetch -
    {
        float* op = out + base + wv * DPW * PLANE + qoff;
        f4a vgA = vg0;
        f4a vgB = *(const f4a*)vp; vp += PLANE;
#pragma unroll 2
        for (int ds = 0; ds < DPW; ++ds) {
            *(f4a*)swr = vgA;                      // ds_write_b128
            if (ds + 2 < DPW) { vgA = *(const f4a*)vp; vp += PLANE; }
            asm volatile("s_waitcnt lgkmcnt(0)" ::: "memory");
            *(float2*)op = PV();
            op += PLANE;
            { f4a tmp = vgB; vgB = vgA; vgA = tmp; }
        }
    }
}

extern "C" void kernel_launch(void* const* d_in, const int* in_sizes, int n_in,
                              void* d_out, int out_size, void* d_ws, size_t ws_size,
                              hipStream_t stream) {
    const float* q = (const float*)d_in[0];
    const float* k = (const float*)d_in[1];
    const float* v = (const float*)d_in[2];
    float* out = (float*)d_out;
    (void)in_sizes; (void)n_in; (void)out_size; (void)d_ws; (void)ws_size;

    const int grid = Bn * 32;  // 1024 blocks x 512 thr -> 4/CU, 32 waves/CU
    dilate_attn_kernel<<<grid, 512, 0, stream>>>(q, k, v, out);
}

// Round 12
// 35.512 us; speedup vs baseline: 3.2386x; 3.2386x over previous
//
#include <hip/hip_runtime.h>

namespace {
constexpr int Bn = 32, Dn = 64, Hn = 64, Wn = 64;
constexpr int PLANE = Hn * Wn;   // 4096
constexpr int NW  = 8;           // waves per block, splitting d
constexpr int DPW = Dn / NW;     // 8 d-slices per wave
constexpr float SCALE = 0.125f;  // 64^-0.5
typedef float f4a __attribute__((ext_vector_type(4), aligned(4)));
}

__global__ __launch_bounds__(512, 8) void dilate_attn_kernel(
    const float* __restrict__ q, const float* __restrict__ k,
    const float* __restrict__ v, float* __restrict__ out)
{
    __shared__ float2 red[NW][9][64];   // 36864 B; 4 blocks/CU = 147 KB

    const int t  = threadIdx.x;
    const int l  = t & 63;
    const int wv = t >> 6;              // wave id -> d-eighth
    const int ci = l & 31;              // lane col-pair index
    const int lr = l >> 5;              // row within stripe
    const int c  = ci * 2;              // first of this lane's 2 pixel cols

    // XCD-chunked swizzle: 1024 blocks -> 128 contiguous (b,stripe) per XCD
    const int bid = blockIdx.x;
    const int swz = (bid & 7) * 128 + (bid >> 3);
    const int b      = swz >> 5;
    const int stripe = swz & 31;
    const int hr     = stripe * 2 + lr; // this lane's pixel row

    const int  base = b * Dn * PLANE;
    const bool ci0 = (ci == 0), ci31 = (ci == 31);

    // Hazard waves: only the global-first plane can read 4B before the buffer
    // (koffU=-1) and only the global-last plane can read past it (koffU=4093).
    // Those waves take the R5 select-remap path (always in-bounds); everyone
    // else runs the select-free uniform-window path, whose edge-lane garbage
    // (prev/next row or plane, valid memory) lands on mask-zeroed positions.
    const bool hazard = ((b == 0) && (wv == 0)) ||
                        ((b == Bn - 1) && (wv == NW - 1));

    int  koffU[3];   // uniform window base: cols c-1..c+2 (fast path)
    int  koffS[3];   // shifted base for edge lanes (slow path, in-bounds)
    bool rok[3];
    const int cbS = ci0 ? 0 : (ci31 ? (c - 2) : (c - 1));
#pragma unroll
    for (int di = 0; di < 3; ++di) {
        const int kr = hr - 1 + di;
        rok[di] = (kr >= 0) && (kr < Hn);
        const int krc = min(max(kr, 0), Hn - 1);
        koffU[di] = krc * Wn + (c - 1);
        koffS[di] = krc * Wn + cbS;
    }
    const int qoff = hr * Wn + c;

    float a0[9], a1[9];
#pragma unroll
    for (int n = 0; n < 9; ++n) { a0[n] = 0.0f; a1[n] = 0.0f; }

    // -------- Phase 1: partial scores over this wave's 8 d-slices ----------
    if (!hazard) {
        const float* kp = k + base + wv * DPW * PLANE;
        const float* qp = q + base + wv * DPW * PLANE;
#pragma unroll 4
        for (int ds = 0; ds < DPW; ++ds) {
            const f4a r0 = *(const f4a*)(kp + koffU[0]);
            const f4a r1 = *(const f4a*)(kp + koffU[1]);
            const f4a r2 = *(const f4a*)(kp + koffU[2]);
            const float2 qv = *(const float2*)(qp + qoff);
            kp += PLANE; qp += PLANE;
#pragma unroll
            for (int di = 0; di < 3; ++di) {
                const f4a vv = (di == 0) ? r0 : (di == 1) ? r1 : r2;
                a0[di * 3 + 0] = fmaf(qv.x, vv.x, a0[di * 3 + 0]);
                a0[di * 3 + 1] = fmaf(qv.x, vv.y, a0[di * 3 + 1]);
                a0[di * 3 + 2] = fmaf(qv.x, vv.z, a0[di * 3 + 2]);
                a1[di * 3 + 0] = fmaf(qv.y, vv.y, a1[di * 3 + 0]);
                a1[di * 3 + 1] = fmaf(qv.y, vv.z, a1[di * 3 + 1]);
                a1[di * 3 + 2] = fmaf(qv.y, vv.w, a1[di * 3 + 2]);
            }
        }
    } else {
        const float* kp = k + base + wv * DPW * PLANE;
        const float* qp = q + base + wv * DPW * PLANE;
#pragma unroll 4
        for (int ds = 0; ds < DPW; ++ds) {
            const f4a r0 = *(const f4a*)(kp + koffS[0]);
            const f4a r1 = *(const f4a*)(kp + koffS[1]);
            const f4a r2 = *(const f4a*)(kp + koffS[2]);
            const float2 qv = *(const float2*)(qp + qoff);
            kp += PLANE; qp += PLANE;
#pragma unroll
            for (int di = 0; di < 3; ++di) {
                const f4a vv = (di == 0) ? r0 : (di == 1) ? r1 : r2;
                const float w0 = ci31 ? vv.y : vv.x;
                const float w1 = ci0 ? vv.x : (ci31 ? vv.z : vv.y);
                const float w2 = ci0 ? vv.y : (ci31 ? vv.w : vv.z);
                const float w3 = ci0 ? vv.z : vv.w;
                a0[di * 3 + 0] = fmaf(qv.x, w0, a0[di * 3 + 0]);
                a0[di * 3 + 1] = fmaf(qv.x, w1, a0[di * 3 + 1]);
                a0[di * 3 + 2] = fmaf(qv.x, w2, a0[di * 3 + 2]);
                a1[di * 3 + 0] = fmaf(qv.y, w1, a1[di * 3 + 0]);
                a1[di * 3 + 1] = fmaf(qv.y, w2, a1[di * 3 + 1]);
                a1[di * 3 + 2] = fmaf(qv.y, w3, a1[di * 3 + 2]);
            }
        }
    }

    // -------- cross-wave reduction: wave wv owns window position n=wv ------
#pragma unroll
    for (int n = 0; n < 9; ++n) red[wv][n][l] = make_float2(a0[n], a1[n]);
    __syncthreads();
    {
        float2 s = red[0][wv][l];
#pragma unroll
        for (int sw = 1; sw < NW; ++sw) {
            const float2 p = red[sw][wv][l];
            s.x += p.x; s.y += p.y;
        }
        red[0][wv][l] = s;
        if (wv == NW - 1) {          // wave 7 also reduces n=8
            float2 s8 = red[0][8][l];
#pragma unroll
            for (int sw = 1; sw < NW; ++sw) {
                const float2 p = red[sw][8][l];
                s8.x += p.x; s8.y += p.y;
            }
            red[0][8][l] = s8;
        }
    }
    __syncthreads();
#pragma unroll
    for (int n = 0; n < 9; ++n) {
        const float2 s = red[0][n][l];
        a0[n] = s.x; a1[n] = s.y;
    }

    // -------- zero invalid-position SCORES (reference: q . 0-pad = 0) -------
#pragma unroll
    for (int di = 0; di < 3; ++di)
#pragma unroll
        for (int dj = 0; dj < 3; ++dj) {
            const int n = di * 3 + dj;
            a0[n] = (rok[di] && (dj != 0 || !ci0))  ? a0[n] : 0.0f;
            a1[n] = (rok[di] && (dj != 2 || !ci31)) ? a1[n] : 0.0f;
        }
#pragma unroll
    for (int n = 0; n < 9; ++n) { a0[n] *= SCALE; a1[n] *= SCALE; }
    float m0 = a0[0], m1 = a1[0];
#pragma unroll
    for (int n = 1; n < 9; ++n) { m0 = fmaxf(m0, a0[n]); m1 = fmaxf(m1, a1[n]); }
    float s0 = 0.0f, s1 = 0.0f;
#pragma unroll
    for (int n = 0; n < 9; ++n) {
        a0[n] = __expf(a0[n] - m0); s0 += a0[n];
        a1[n] = __expf(a1[n] - m1); s1 += a1[n];
    }
    const float i0 = 1.0f / s0, i1 = 1.0f / s1;
#pragma unroll
    for (int n = 0; n < 9; ++n) { a0[n] *= i0; a1[n] *= i1; }

    // -------- zero invalid-position WEIGHTS (reference: attn * v=0 there) ---
#pragma unroll
    for (int di = 0; di < 3; ++di)
#pragma unroll
        for (int dj = 0; dj < 3; ++dj) {
            const int n = di * 3 + dj;
            a0[n] = (rok[di] && (dj != 0 || !ci0))  ? a0[n] : 0.0f;
            a1[n] = (rok[di] && (dj != 2 || !ci31)) ? a1[n] : 0.0f;
        }

    // -------- Phase 2: out = attn . v_window for this wave's d-eighth -------
    if (!hazard) {
        const float* vp = v + base + wv * DPW * PLANE;
        float*       op = out + base + wv * DPW * PLANE;
#pragma unroll 4
        for (int ds = 0; ds < DPW; ++ds) {
            const f4a r0 = *(const f4a*)(vp + koffU[0]);
            const f4a r1 = *(const f4a*)(vp + koffU[1]);
            const f4a r2 = *(const f4a*)(vp + koffU[2]);
            vp += PLANE;
            float o0 = 0.0f, o1 = 0.0f;
#pragma unroll
            for (int di = 0; di < 3; ++di) {
                const f4a vv = (di == 0) ? r0 : (di == 1) ? r1 : r2;
                o0 = fmaf(a0[di * 3 + 0], vv.x, o0);
                o0 = fmaf(a0[di * 3 + 1], vv.y, o0);
                o0 = fmaf(a0[di * 3 + 2], vv.z, o0);
                o1 = fmaf(a1[di * 3 + 0], vv.y, o1);
                o1 = fmaf(a1[di * 3 + 1], vv.z, o1);
                o1 = fmaf(a1[di * 3 + 2], vv.w, o1);
            }
            *(float2*)(op + qoff) = make_float2(o0, o1);
            op += PLANE;
        }
    } else {
        const float* vp = v + base + wv * DPW * PLANE;
        float*       op = out + base + wv * DPW * PLANE;
#pragma unroll 4
        for (int ds = 0; ds < DPW; ++ds) {
            const f4a r0 = *(const f4a*)(vp + koffS[0]);
            const f4a r1 = *(const f4a*)(vp + koffS[1]);
            const f4a r2 = *(const f4a*)(vp + koffS[2]);
            vp += PLANE;
            float o0 = 0.0f, o1 = 0.0f;
#pragma unroll
            for (int di = 0; di < 3; ++di) {
                const f4a vv = (di == 0) ? r0 : (di == 1) ? r1 : r2;
                const float w0 = ci31 ? vv.y : vv.x;
                const float w1 = ci0 ? vv.x : (ci31 ? vv.z : vv.y);
                const float w2 = ci0 ? vv.y : (ci31 ? vv.w : vv.z);
                const float w3 = ci0 ? vv.z : vv.w;
                o0 = fmaf(a0[di * 3 + 0], w0, o0);
                o0 = fmaf(a0[di * 3 + 1], w1, o0);
                o0 = fmaf(a0[di * 3 + 2], w2, o0);
                o1 = fmaf(a1[di * 3 + 0], w1, o1);
                o1 = fmaf(a1[di * 3 + 1], w2, o1);
                o1 = fmaf(a1[di * 3 + 2], w3, o1);
            }
            *(float2*)(op + qoff) = make_float2(o0, o1);
            op += PLANE;
        }
    }
}

extern "C" void kernel_launch(void* const* d_in, const int* in_sizes, int n_in,
                              void* d_out, int out_size, void* d_ws, size_t ws_size,
                              hipStream_t stream) {
    const float* q = (const float*)d_in[0];
    const float* k = (const float*)d_in[1];
    const float* v = (const float*)d_in[2];
    float* out = (float*)d_out;
    (void)in_sizes; (void)n_in; (void)out_size; (void)d_ws; (void)ws_size;

    const int grid = Bn * 32;  // 1024 blocks x 512 thr -> 4/CU, 32 waves/CU
    dilate_attn_kernel<<<grid, 512, 0, stream>>>(q, k, v, out);
}